// Round 1
// baseline (573.440 us; speedup 1.0000x reference)
//
#include <hip/hip_runtime.h>

// Problem constants
constexpr int Bn   = 32;
constexpr int CIN  = 64;
constexpr int Lx   = 8192;
constexpr int L1   = 8190;   // length after kw=3,d=1 VALID conv
constexpr int LOUT = 8186;   // final output length
constexpr int NCH  = 384;    // 3 * 128 output channels

constexpr int TB = 256;      // threads per block
constexpr int TT = 256;      // time-tile per block
constexpr int NTILES = (LOUT + TT - 1) / TT;  // 32

// Pre-transpose stage-1 weights into ws: layout [ci][64] with first 54 =
// (k,j) -> k*3+j, k = 0..5: w7_1 row k, 6..11: w10_1, 12..17: w15_1.
// Branch BR's 18 weights for channel ci live at ws[ci*64 + BR*18 .. +18).
__global__ void prep_weights(const float* __restrict__ w7_1,
                             const float* __restrict__ w10_1,
                             const float* __restrict__ w15_1,
                             float* __restrict__ ws) {
    int idx = blockIdx.x * blockDim.x + threadIdx.x;
    if (idx >= 64 * 54) return;
    int ci = idx / 54, r = idx % 54;
    int k = r / 3, j = r % 3;
    const float* src = (k < 6) ? w7_1 : ((k < 12) ? w10_1 : w15_1);
    int kk = (k < 6) ? k : ((k < 12) ? k - 6 : k - 12);
    ws[ci * 64 + r] = src[kk * 192 + ci * 3 + j];
}

// One block = one (tile, branch, batch). Branch split triples block count
// (12 blocks/CU) and cuts per-wave serial work 3x; __launch_bounds__(256,8)
// caps VGPR at 64 so 8 blocks/CU are resident -> 8 waves/SIMD to hide the
// stage-1 global-load and stage-3 s_load latency that bounded the old kernel.
template <int BR>
__device__ __forceinline__ void run_branch(
    float* __restrict__ smem,
    const float* __restrict__ xb,      // x for this batch
    const float* __restrict__ wS1,     // prepped stage-1 weights [ci][64]
    const float* __restrict__ wmid,    // stage-2 weights (6 x 18), null for BR0
    const float* __restrict__ wlast,   // stage-3 weights (128 x NW)
    float* __restrict__ outb,          // out + (b*NCH + BR*128)*LOUT
    int t0)
{
    constexpr int PRE = (BR == 0) ? 0 : (BR == 1 ? 4 : 8);  // causal look-back
    constexpr int NA  = TT + 4 + PRE;   // stage-1 window [t0-PRE, t0+TT+4)
    constexpr int NB  = NA - 4;         // stage-2 window [t0-PRE, t0+TT)
    float* ha = smem;                   // [6][NA]
    float* hb = smem + 6 * NA;          // [6][NB]
    const int tid = threadIdx.x;

    // -------- phase 1: 64->6 conv, kw=3, d=1 (branch-specific 6 channels) --
    for (int p = tid; p < NA; p += TB) {
        const int s = t0 - PRE + p;
        float a[6];
        #pragma unroll
        for (int c = 0; c < 6; ++c) a[c] = 0.f;
        if (s >= 0 && s < L1) {
            const float* xr = xb + s;
            const float* wr = wS1 + BR * 18;   // wave-uniform -> s_load
            for (int ci = 0; ci < CIN; ++ci) {
                const float x0 = xr[0];
                const float x1 = xr[1];
                const float x2 = xr[2];
                #pragma unroll
                for (int c = 0; c < 6; ++c) {
                    a[c] = fmaf(wr[c * 3 + 0], x0, a[c]);
                    a[c] = fmaf(wr[c * 3 + 1], x1, a[c]);
                    a[c] = fmaf(wr[c * 3 + 2], x2, a[c]);
                }
                xr += Lx;
                wr += 64;
            }
            #pragma unroll
            for (int c = 0; c < 6; ++c) a[c] = fmaxf(a[c], 0.f);
        }
        #pragma unroll
        for (int c = 0; c < 6; ++c) ha[c * NA + p] = a[c];
    }
    __syncthreads();

    // -------- phase 2: 6->6 conv, kw=3, d=2 (branches 1,2 only) ------------
    if (BR != 0) {
        for (int q = tid; q < NB; q += TB) {
            const int u = t0 - PRE + q;
            float v[18];
            #pragma unroll
            for (int c = 0; c < 6; ++c)
                #pragma unroll
                for (int j = 0; j < 3; ++j)
                    v[c * 3 + j] = ha[c * NA + q + 2 * j];
            #pragma unroll
            for (int k = 0; k < 6; ++k) {
                float acc = 0.f;
                #pragma unroll
                for (int r = 0; r < 18; ++r)
                    acc = fmaf(wmid[k * 18 + r], v[r], acc);
                hb[k * NB + q] = (u >= 0) ? fmaxf(acc, 0.f) : 0.f;  // causal pad
            }
        }
    }
    __syncthreads();

    // -------- phase 3: 6->128 final conv + relu + coalesced store ----------
    // 1 output position per lane: t = t0 + tid; each wave stores 256B/instr.
    const int t = t0 + tid;
    const bool ok = (t < LOUT);
    constexpr int NW = (BR == 1) ? 12 : 18;   // weights per output channel
    float v[NW];
    if (BR == 0) {
        // out[t] = sum_j w[c,j] * h7[t + 2j]
        #pragma unroll
        for (int c = 0; c < 6; ++c)
            #pragma unroll
            for (int j = 0; j < 3; ++j)
                v[c * 3 + j] = ha[c * NA + tid + 2 * j];
    } else if (BR == 1) {
        // out[t] = sum_j w[c,j] * h10b[t - 4 + 4j], j in {0,1}
        #pragma unroll
        for (int c = 0; c < 6; ++c)
            #pragma unroll
            for (int j = 0; j < 2; ++j)
                v[c * 2 + j] = hb[c * NB + tid + 4 * j];
    } else {
        // out[t] = sum_j w[c,j] * h15b[t - 8 + 4j], j in {0,1,2}
        #pragma unroll
        for (int c = 0; c < 6; ++c)
            #pragma unroll
            for (int j = 0; j < 3; ++j)
                v[c * 3 + j] = hb[c * NB + tid + 4 * j];
    }
    #pragma unroll 4
    for (int oc = 0; oc < 128; ++oc) {
        const float* wp = wlast + oc * NW;    // wave-uniform -> s_load
        float acc = 0.f;
        #pragma unroll
        for (int r = 0; r < NW; ++r) acc = fmaf(wp[r], v[r], acc);
        if (ok) outb[(size_t)oc * LOUT + t] = fmaxf(acc, 0.f);
    }
}

__global__ __launch_bounds__(TB, 8)
void fused_inception(const float* __restrict__ x,
                     const float* __restrict__ wS1,   // d_ws, [64][64]
                     const float* __restrict__ w7_3,
                     const float* __restrict__ w10_3,
                     const float* __restrict__ w10_5,
                     const float* __restrict__ w15_3,
                     const float* __restrict__ w15_5,
                     float* __restrict__ out) {
    // max footprint: ha 6*268 + hb 6*264 = 12768 B
    __shared__ float smem[6 * 268 + 6 * 264];
    const int tile = blockIdx.x;
    const int br   = blockIdx.y;
    const int b    = blockIdx.z;
    const int t0   = tile * TT;
    const float* xb = x + (size_t)b * CIN * Lx;
    float* outb = out + ((size_t)b * NCH + (size_t)br * 128) * LOUT;

    if (br == 0)      run_branch<0>(smem, xb, wS1, nullptr, w7_3,  outb, t0);
    else if (br == 1) run_branch<1>(smem, xb, wS1, w10_3,  w10_5, outb, t0);
    else              run_branch<2>(smem, xb, wS1, w15_3,  w15_5, outb, t0);
}

extern "C" void kernel_launch(void* const* d_in, const int* in_sizes, int n_in,
                              void* d_out, int out_size, void* d_ws, size_t ws_size,
                              hipStream_t stream) {
    const float* x     = (const float*)d_in[0];
    const float* w7_1  = (const float*)d_in[1];
    const float* w7_3  = (const float*)d_in[2];
    const float* w10_1 = (const float*)d_in[3];
    const float* w10_3 = (const float*)d_in[4];
    const float* w10_5 = (const float*)d_in[5];
    const float* w15_1 = (const float*)d_in[6];
    const float* w15_3 = (const float*)d_in[7];
    const float* w15_5 = (const float*)d_in[8];
    float* out = (float*)d_out;
    float* ws  = (float*)d_ws;   // 64*64 floats = 16 KB used

    prep_weights<<<dim3(14), dim3(256), 0, stream>>>(w7_1, w10_1, w15_1, ws);
    fused_inception<<<dim3(NTILES, 3, Bn), dim3(TB), 0, stream>>>(
        x, ws, w7_3, w10_3, w10_5, w15_3, w15_5, out);
}